// Round 1
// baseline (4123.862 us; speedup 1.0000x reference)
//
#include <hip/hip_runtime.h>

// Problem constants (from reference)
#define NL0 300000
#define NL1 60000
#define NL2 15000
#define NL3 4000
#define NE0 960000
#define NE1 240000
#define NE2 64000
#define F_IN 256
#define F_HID 128
#define F_OUT 47

// ---------------------------------------------------------------------------
// Kernel 1: per-dst edge counts (float, so we can divide later)
// ---------------------------------------------------------------------------
__global__ void count_edges(const int* __restrict__ dst, int E, float* __restrict__ cnt) {
    int i = blockIdx.x * blockDim.x + threadIdx.x;
    if (i < E) atomicAdd(&cnt[dst[i]], 1.0f);
}

// ---------------------------------------------------------------------------
// Kernel 2: scatter-add of gathered rows.  One thread per (edge, float4 chunk).
// Lanes 0..F/4-1 of consecutive threads cover one edge's row -> coalesced
// 16B/lane reads; atomics go to consecutive addresses of one dst row.
// ---------------------------------------------------------------------------
template <int F>
__global__ void scatter_add4(const float4* __restrict__ h,
                             const int* __restrict__ src,
                             const int* __restrict__ dst,
                             int E,
                             float4* __restrict__ acc) {
    constexpr int FV = F / 4;
    long long idx = (long long)blockIdx.x * blockDim.x + threadIdx.x;
    if (idx >= (long long)E * FV) return;
    int e = (int)(idx / FV);
    int f = (int)(idx % FV);
    float4 v = h[(long long)src[e] * FV + f];
    float* a = (float*)&acc[(long long)dst[e] * FV + f];
    atomicAdd(a + 0, v.x);
    atomicAdd(a + 1, v.y);
    atomicAdd(a + 2, v.z);
    atomicAdd(a + 3, v.w);
}

// ---------------------------------------------------------------------------
// Kernel 3: fused mean (divide by count) + linear (+ optional relu).
// One block per dst row.  Row staged in LDS; thread j computes output col j.
// ---------------------------------------------------------------------------
template <int FINv, int FOUTv, bool RELU>
__global__ void mean_linear(const float* __restrict__ acc,
                            const float* __restrict__ cnt,
                            const float* __restrict__ W,   // [FINv, FOUTv] row-major
                            const float* __restrict__ b,   // [FOUTv]
                            float* __restrict__ out,       // [N, FOUTv]
                            int N) {
    __shared__ float row[FINv];
    int r = blockIdx.x;
    if (r >= N) return;
    float inv = 1.0f / fmaxf(cnt[r], 1.0f);
    for (int k = threadIdx.x; k < FINv; k += blockDim.x)
        row[k] = acc[(long long)r * FINv + k] * inv;
    __syncthreads();
    int j = threadIdx.x;
    if (j < FOUTv) {
        float s = b[j];
#pragma unroll 8
        for (int k = 0; k < FINv; ++k)
            s += row[k] * W[k * FOUTv + j];
        out[(long long)r * FOUTv + j] = RELU ? fmaxf(s, 0.0f) : s;
    }
}

// ---------------------------------------------------------------------------

static inline size_t align256(size_t x) { return (x + 255) & ~size_t(255); }

extern "C" void kernel_launch(void* const* d_in, const int* in_sizes, int n_in,
                              void* d_out, int out_size, void* d_ws, size_t ws_size,
                              hipStream_t stream) {
    const float* features = (const float*)d_in[0];
    const int*   src0     = (const int*)d_in[1];
    const int*   dst0     = (const int*)d_in[2];
    const int*   src1     = (const int*)d_in[3];
    const int*   dst1     = (const int*)d_in[4];
    const int*   src2     = (const int*)d_in[5];
    const int*   dst2     = (const int*)d_in[6];
    const float* W1       = (const float*)d_in[7];
    const float* b1       = (const float*)d_in[8];
    const float* W2       = (const float*)d_in[9];
    const float* b2       = (const float*)d_in[10];
    const float* W3       = (const float*)d_in[11];
    const float* b3       = (const float*)d_in[12];
    float* out = (float*)d_out;

    // Workspace layout
    char* p = (char*)d_ws;
    size_t off = 0;
    auto alloc = [&](size_t bytes) {
        char* r = p + off;
        off += align256(bytes);
        return r;
    };
    float* cnt0 = (float*)alloc(sizeof(float) * NL1);
    float* acc0 = (float*)alloc(sizeof(float) * (size_t)NL1 * F_IN);
    float* h1   = (float*)alloc(sizeof(float) * (size_t)NL1 * F_HID);
    float* cnt1 = (float*)alloc(sizeof(float) * NL2);
    float* acc1 = (float*)alloc(sizeof(float) * (size_t)NL2 * F_HID);
    float* h2   = (float*)alloc(sizeof(float) * (size_t)NL2 * F_HID);
    float* cnt2 = (float*)alloc(sizeof(float) * NL3);
    float* acc2 = (float*)alloc(sizeof(float) * (size_t)NL3 * F_HID);
    (void)ws_size;

    // ---- Layer 0 -> 1: mean_agg(features) @ W1 + b1, relu ----
    hipMemsetAsync(cnt0, 0, sizeof(float) * NL1, stream);
    hipMemsetAsync(acc0, 0, sizeof(float) * (size_t)NL1 * F_IN, stream);
    count_edges<<<(NE0 + 255) / 256, 256, 0, stream>>>(dst0, NE0, cnt0);
    {
        long long total = (long long)NE0 * (F_IN / 4);
        int grid = (int)((total + 255) / 256);
        scatter_add4<F_IN><<<grid, 256, 0, stream>>>(
            (const float4*)features, src0, dst0, NE0, (float4*)acc0);
    }
    mean_linear<F_IN, F_HID, true><<<NL1, 128, 0, stream>>>(acc0, cnt0, W1, b1, h1, NL1);

    // ---- Layer 1 -> 2: mean_agg(h1) @ W2 + b2, relu ----
    hipMemsetAsync(cnt1, 0, sizeof(float) * NL2, stream);
    hipMemsetAsync(acc1, 0, sizeof(float) * (size_t)NL2 * F_HID, stream);
    count_edges<<<(NE1 + 255) / 256, 256, 0, stream>>>(dst1, NE1, cnt1);
    {
        long long total = (long long)NE1 * (F_HID / 4);
        int grid = (int)((total + 255) / 256);
        scatter_add4<F_HID><<<grid, 256, 0, stream>>>(
            (const float4*)h1, src1, dst1, NE1, (float4*)acc1);
    }
    mean_linear<F_HID, F_HID, true><<<NL2, 128, 0, stream>>>(acc1, cnt1, W2, b2, h2, NL2);

    // ---- Layer 2 -> 3: mean_agg(h2) @ W3 + b3 (no relu) ----
    hipMemsetAsync(cnt2, 0, sizeof(float) * NL3, stream);
    hipMemsetAsync(acc2, 0, sizeof(float) * (size_t)NL3 * F_HID, stream);
    count_edges<<<(NE2 + 255) / 256, 256, 0, stream>>>(dst2, NE2, cnt2);
    {
        long long total = (long long)NE2 * (F_HID / 4);
        int grid = (int)((total + 255) / 256);
        scatter_add4<F_HID><<<grid, 256, 0, stream>>>(
            (const float4*)h2, src2, dst2, NE2, (float4*)acc2);
    }
    mean_linear<F_HID, F_OUT, false><<<NL3, 64, 0, stream>>>(acc2, cnt2, W3, b3, out, NL3);
}

// Round 2
// 485.523 us; speedup vs baseline: 8.4937x; 8.4937x over previous
//
#include <hip/hip_runtime.h>

// Problem constants (from reference)
#define NL0 300000
#define NL1 60000
#define NL2 15000
#define NL3 4000
#define NE0 960000
#define NE1 240000
#define NE2 64000
#define F_IN 256
#define F_HID 128
#define F_OUT 47

// ---------------------------------------------------------------------------
// Wave-wide (64-lane) inclusive scan
// ---------------------------------------------------------------------------
__device__ inline int wave_incl_scan(int v) {
    int lane = threadIdx.x & 63;
#pragma unroll
    for (int off = 1; off < 64; off <<= 1) {
        int t = __shfl_up(v, off, 64);
        if (lane >= off) v += t;
    }
    return v;
}

// ---------------------------------------------------------------------------
// CSR build step 1: histogram of dst
// ---------------------------------------------------------------------------
__global__ void histogram(const int* __restrict__ dst, int E, int* __restrict__ cnt) {
    int i = blockIdx.x * blockDim.x + threadIdx.x;
    if (i < E) atomicAdd(&cnt[dst[i]], 1);
}

// ---------------------------------------------------------------------------
// CSR build step 2a: per-1024-chunk exclusive scan (writes chunk-local excl
// into row_start, chunk totals into blocksum)
// ---------------------------------------------------------------------------
__global__ __launch_bounds__(1024) void scan_block(const int* __restrict__ cnt, int N,
                                                   int* __restrict__ row_start,
                                                   int* __restrict__ blocksum) {
    __shared__ int wsum[16];
    int i = blockIdx.x * 1024 + threadIdx.x;
    int lane = threadIdx.x & 63, wid = threadIdx.x >> 6;
    int v = (i < N) ? cnt[i] : 0;
    int incl = wave_incl_scan(v);
    if (lane == 63) wsum[wid] = incl;
    __syncthreads();
    if (threadIdx.x < 16) {
        int w = wsum[threadIdx.x];
#pragma unroll
        for (int off = 1; off < 16; off <<= 1) {
            int t = __shfl_up(w, off, 64);
            if ((int)threadIdx.x >= off) w += t;
        }
        wsum[threadIdx.x] = w;
    }
    __syncthreads();
    int woff = wid ? wsum[wid - 1] : 0;
    if (i < N) row_start[i] = woff + incl - v;
    if (threadIdx.x == 0) blocksum[blockIdx.x] = wsum[15];
}

// step 2b: exclusive-scan the (<=64) chunk totals in place
__global__ void scan_totals(int* __restrict__ bs, int nb) {
    int lane = threadIdx.x;
    int v = (lane < nb) ? bs[lane] : 0;
    int incl = wave_incl_scan(v);
    if (lane < nb) bs[lane] = incl - v;
}

// step 2c: add chunk offsets; produce row_start (+sentinel) and cursor copy
__global__ __launch_bounds__(1024) void add_offsets(int* __restrict__ row_start,
                                                    const int* __restrict__ bs, int N, int E,
                                                    int* __restrict__ cursor) {
    int i = blockIdx.x * 1024 + threadIdx.x;
    if (i < N) {
        int s = row_start[i] + bs[blockIdx.x];
        row_start[i] = s;
        cursor[i] = s;
    }
    if (i == 0) row_start[N] = E;
}

// ---------------------------------------------------------------------------
// CSR build step 3: scatter edge src ids into dst-grouped order
// ---------------------------------------------------------------------------
__global__ void fill_csr(const int* __restrict__ src, const int* __restrict__ dst, int E,
                         int* __restrict__ cursor, int* __restrict__ sorted_src) {
    int i = blockIdx.x * blockDim.x + threadIdx.x;
    if (i < E) {
        int p = atomicAdd(&cursor[dst[i]], 1);
        sorted_src[p] = src[i];
    }
}

// ---------------------------------------------------------------------------
// Aggregation: one 64-lane wave per dst row.  Lane l holds F/64 floats of the
// row in registers; edges streamed with coalesced vector loads; single write.
// Mean division folded in (cnt==0 -> 0, matching ref's sum 0 / max(0,1)).
// ---------------------------------------------------------------------------
template <int F>
__global__ __launch_bounds__(256) void csr_mean_gather(const float* __restrict__ h,
                                                       const int* __restrict__ row_start,
                                                       const int* __restrict__ sorted_src,
                                                       float* __restrict__ outmean, int N) {
    int lane = threadIdx.x & 63;
    int r = (int)((blockIdx.x * blockDim.x + threadIdx.x) >> 6);
    if (r >= N) return;
    int s0 = row_start[r], s1 = row_start[r + 1];
    float inv = (s1 > s0) ? 1.0f / (float)(s1 - s0) : 0.0f;

    if constexpr (F == 256) {
        float4 acc = make_float4(0.f, 0.f, 0.f, 0.f);
        int e = s0;
        for (; e + 1 < s1; e += 2) {
            int sa = sorted_src[e], sb = sorted_src[e + 1];
            float4 va = *(const float4*)(h + (size_t)sa * F + lane * 4);
            float4 vb = *(const float4*)(h + (size_t)sb * F + lane * 4);
            acc.x += va.x + vb.x;
            acc.y += va.y + vb.y;
            acc.z += va.z + vb.z;
            acc.w += va.w + vb.w;
        }
        if (e < s1) {
            int sa = sorted_src[e];
            float4 va = *(const float4*)(h + (size_t)sa * F + lane * 4);
            acc.x += va.x; acc.y += va.y; acc.z += va.z; acc.w += va.w;
        }
        float4 o = make_float4(acc.x * inv, acc.y * inv, acc.z * inv, acc.w * inv);
        *(float4*)(outmean + (size_t)r * F + lane * 4) = o;
    } else {
        float2 acc = make_float2(0.f, 0.f);
        int e = s0;
        for (; e + 1 < s1; e += 2) {
            int sa = sorted_src[e], sb = sorted_src[e + 1];
            float2 va = *(const float2*)(h + (size_t)sa * F + lane * 2);
            float2 vb = *(const float2*)(h + (size_t)sb * F + lane * 2);
            acc.x += va.x + vb.x;
            acc.y += va.y + vb.y;
        }
        if (e < s1) {
            int sa = sorted_src[e];
            float2 va = *(const float2*)(h + (size_t)sa * F + lane * 2);
            acc.x += va.x; acc.y += va.y;
        }
        *(float2*)(outmean + (size_t)r * F + lane * 2) = make_float2(acc.x * inv, acc.y * inv);
    }
}

// ---------------------------------------------------------------------------
// Linear (+bias, +optional relu): 8 rows per block staged in LDS, 256 threads.
// CTH = padded output cols per row-group; each thread owns RPB/(256/CTH) rows
// of one output column.
// ---------------------------------------------------------------------------
template <int FIN, int FOUT, int CTH, int RPB, bool RELU>
__global__ __launch_bounds__(256) void linear_kernel(const float* __restrict__ in,
                                                     const float* __restrict__ W,
                                                     const float* __restrict__ b,
                                                     float* __restrict__ out, int N) {
    constexpr int RG = 256 / CTH;   // row groups
    constexpr int RPT = RPB / RG;   // rows per thread
    __shared__ __align__(16) float rows[RPB][FIN];
    int rbase = blockIdx.x * RPB;

    for (int idx = threadIdx.x * 4; idx < RPB * FIN; idx += 256 * 4) {
        *(float4*)&rows[0][idx] = *(const float4*)&in[(size_t)rbase * FIN + idx];
    }
    __syncthreads();

    int j = threadIdx.x % CTH;
    int rg = threadIdx.x / CTH;
    if (j < FOUT) {
        float acc[RPT];
#pragma unroll
        for (int r = 0; r < RPT; ++r) acc[r] = 0.f;
#pragma unroll 8
        for (int k = 0; k < FIN; ++k) {
            float w = W[k * FOUT + j];
#pragma unroll
            for (int r = 0; r < RPT; ++r)
                acc[r] += rows[rg * RPT + r][k] * w;
        }
        float bb = b[j];
#pragma unroll
        for (int r = 0; r < RPT; ++r) {
            float v = acc[r] + bb;
            if (RELU) v = fmaxf(v, 0.f);
            out[(size_t)(rbase + rg * RPT + r) * FOUT + j] = v;
        }
    }
}

// ---------------------------------------------------------------------------

static inline size_t align256(size_t x) { return (x + 255) & ~size_t(255); }

extern "C" void kernel_launch(void* const* d_in, const int* in_sizes, int n_in,
                              void* d_out, int out_size, void* d_ws, size_t ws_size,
                              hipStream_t stream) {
    const float* features = (const float*)d_in[0];
    const int*   src0     = (const int*)d_in[1];
    const int*   dst0     = (const int*)d_in[2];
    const int*   src1     = (const int*)d_in[3];
    const int*   dst1     = (const int*)d_in[4];
    const int*   src2     = (const int*)d_in[5];
    const int*   dst2     = (const int*)d_in[6];
    const float* W1       = (const float*)d_in[7];
    const float* b1       = (const float*)d_in[8];
    const float* W2       = (const float*)d_in[9];
    const float* b2       = (const float*)d_in[10];
    const float* W3       = (const float*)d_in[11];
    const float* b3       = (const float*)d_in[12];
    float* out = (float*)d_out;

    // Workspace layout
    char* p = (char*)d_ws;
    size_t off = 0;
    auto alloc = [&](size_t bytes) {
        char* r = p + off;
        off += align256(bytes);
        return r;
    };
    // float buffers
    float* mean0 = (float*)alloc(sizeof(float) * (size_t)NL1 * F_IN);
    float* h1    = (float*)alloc(sizeof(float) * (size_t)NL1 * F_HID);
    float* mean1 = (float*)alloc(sizeof(float) * (size_t)NL2 * F_HID);
    float* h2    = (float*)alloc(sizeof(float) * (size_t)NL2 * F_HID);
    float* mean2 = (float*)alloc(sizeof(float) * (size_t)NL3 * F_HID);
    // int buffers (per layer: cnt, row_start, cursor, blocksum, sorted_src)
    int* cnt0 = (int*)alloc(sizeof(int) * NL1);
    int* rs0  = (int*)alloc(sizeof(int) * (NL1 + 1));
    int* cur0 = (int*)alloc(sizeof(int) * NL1);
    int* bs0  = (int*)alloc(sizeof(int) * 64);
    int* ss0  = (int*)alloc(sizeof(int) * NE0);
    int* cnt1 = (int*)alloc(sizeof(int) * NL2);
    int* rs1  = (int*)alloc(sizeof(int) * (NL2 + 1));
    int* cur1 = (int*)alloc(sizeof(int) * NL2);
    int* bs1  = (int*)alloc(sizeof(int) * 64);
    int* ss1  = (int*)alloc(sizeof(int) * NE1);
    int* cnt2 = (int*)alloc(sizeof(int) * NL3);
    int* rs2  = (int*)alloc(sizeof(int) * (NL3 + 1));
    int* cur2 = (int*)alloc(sizeof(int) * NL3);
    int* bs2  = (int*)alloc(sizeof(int) * 64);
    int* ss2  = (int*)alloc(sizeof(int) * NE2);
    (void)ws_size;

    auto build_csr = [&](const int* src, const int* dst, int E, int N,
                         int* cnt, int* rs, int* cur, int* bs, int* ss) {
        hipMemsetAsync(cnt, 0, sizeof(int) * N, stream);
        histogram<<<(E + 255) / 256, 256, 0, stream>>>(dst, E, cnt);
        int nb = (N + 1023) / 1024;
        scan_block<<<nb, 1024, 0, stream>>>(cnt, N, rs, bs);
        scan_totals<<<1, 64, 0, stream>>>(bs, nb);
        add_offsets<<<nb, 1024, 0, stream>>>(rs, bs, N, E, cur);
        fill_csr<<<(E + 255) / 256, 256, 0, stream>>>(src, dst, E, cur, ss);
    };

    // ---- Layer 0 -> 1 ----
    build_csr(src0, dst0, NE0, NL1, cnt0, rs0, cur0, bs0, ss0);
    csr_mean_gather<F_IN><<<(NL1 + 3) / 4, 256, 0, stream>>>(features, rs0, ss0, mean0, NL1);
    linear_kernel<F_IN, F_HID, 128, 8, true><<<NL1 / 8, 256, 0, stream>>>(mean0, W1, b1, h1, NL1);

    // ---- Layer 1 -> 2 ----
    build_csr(src1, dst1, NE1, NL2, cnt1, rs1, cur1, bs1, ss1);
    csr_mean_gather<F_HID><<<(NL2 + 3) / 4, 256, 0, stream>>>(h1, rs1, ss1, mean1, NL2);
    linear_kernel<F_HID, F_HID, 128, 8, true><<<NL2 / 8, 256, 0, stream>>>(mean1, W2, b2, h2, NL2);

    // ---- Layer 2 -> 3 ----
    build_csr(src2, dst2, NE2, NL3, cnt2, rs2, cur2, bs2, ss2);
    csr_mean_gather<F_HID><<<(NL3 + 3) / 4, 256, 0, stream>>>(h2, rs2, ss2, mean2, NL3);
    linear_kernel<F_HID, F_OUT, 64, 8, false><<<NL3 / 8, 256, 0, stream>>>(mean2, W3, b3, out, NL3);
}

// Round 3
// 477.509 us; speedup vs baseline: 8.6362x; 1.0168x over previous
//
#include <hip/hip_runtime.h>

// Problem constants (from reference)
#define NL0 300000
#define NL1 60000
#define NL2 15000
#define NL3 4000
#define NE0 960000
#define NE1 240000
#define NE2 64000
#define F_IN 256
#define F_HID 128
#define F_OUT 47
#define THR0 150000   // src split threshold for layer-0 L3 blocking

// ---------------------------------------------------------------------------
// Wave-wide (64-lane) inclusive scan
// ---------------------------------------------------------------------------
__device__ inline int wave_incl_scan(int v) {
    int lane = threadIdx.x & 63;
#pragma unroll
    for (int off = 1; off < 64; off <<= 1) {
        int t = __shfl_up(v, off, 64);
        if (lane >= off) v += t;
    }
    return v;
}

// ---------------------------------------------------------------------------
// CSR build: histograms (plain and src-split variants)
// ---------------------------------------------------------------------------
__global__ void histogram(const int* __restrict__ dst, int E, int* __restrict__ cnt) {
    int i = blockIdx.x * blockDim.x + threadIdx.x;
    if (i < E) atomicAdd(&cnt[dst[i]], 1);
}

__global__ void histogram_split(const int* __restrict__ dst, const int* __restrict__ src,
                                int E, int thr, int* __restrict__ cnt) {
    int i = blockIdx.x * blockDim.x + threadIdx.x;
    if (i < E) atomicAdd(&cnt[dst[i] * 2 + (src[i] >= thr)], 1);
}

// ---------------------------------------------------------------------------
// CSR build: exclusive scan (chunked, up to 1024*1024 elements)
// ---------------------------------------------------------------------------
__global__ __launch_bounds__(1024) void scan_block(const int* __restrict__ cnt, int N,
                                                   int* __restrict__ row_start,
                                                   int* __restrict__ blocksum) {
    __shared__ int wsum[16];
    int i = blockIdx.x * 1024 + threadIdx.x;
    int lane = threadIdx.x & 63, wid = threadIdx.x >> 6;
    int v = (i < N) ? cnt[i] : 0;
    int incl = wave_incl_scan(v);
    if (lane == 63) wsum[wid] = incl;
    __syncthreads();
    if (threadIdx.x < 16) {
        int w = wsum[threadIdx.x];
#pragma unroll
        for (int off = 1; off < 16; off <<= 1) {
            int t = __shfl_up(w, off, 64);
            if ((int)threadIdx.x >= off) w += t;
        }
        wsum[threadIdx.x] = w;
    }
    __syncthreads();
    int woff = wid ? wsum[wid - 1] : 0;
    if (i < N) row_start[i] = woff + incl - v;
    if (threadIdx.x == 0) blocksum[blockIdx.x] = wsum[15];
}

// exclusive-scan the (<=1024) chunk totals in place (single block, 1024 thr)
__global__ __launch_bounds__(1024) void scan_totals(int* __restrict__ bs, int nb) {
    __shared__ int wsum[16];
    int i = threadIdx.x;
    int lane = i & 63, wid = i >> 6;
    int v = (i < nb) ? bs[i] : 0;
    int incl = wave_incl_scan(v);
    if (lane == 63) wsum[wid] = incl;
    __syncthreads();
    if (i < 16) {
        int w = wsum[i];
#pragma unroll
        for (int off = 1; off < 16; off <<= 1) {
            int t = __shfl_up(w, off, 64);
            if (i >= off) w += t;
        }
        wsum[i] = w;
    }
    __syncthreads();
    int woff = wid ? wsum[wid - 1] : 0;
    if (i < nb) bs[i] = woff + incl - v;
}

__global__ __launch_bounds__(1024) void add_offsets(int* __restrict__ row_start,
                                                    const int* __restrict__ bs, int N, int E,
                                                    int* __restrict__ cursor) {
    int i = blockIdx.x * 1024 + threadIdx.x;
    if (i < N) {
        int s = row_start[i] + bs[blockIdx.x];
        row_start[i] = s;
        cursor[i] = s;
    }
    if (i == 0) row_start[N] = E;
}

// ---------------------------------------------------------------------------
// CSR build: scatter edge src ids into grouped order
// ---------------------------------------------------------------------------
__global__ void fill_csr(const int* __restrict__ src, const int* __restrict__ dst, int E,
                         int* __restrict__ cursor, int* __restrict__ sorted_src) {
    int i = blockIdx.x * blockDim.x + threadIdx.x;
    if (i < E) {
        int p = atomicAdd(&cursor[dst[i]], 1);
        sorted_src[p] = src[i];
    }
}

__global__ void fill_csr_split(const int* __restrict__ src, const int* __restrict__ dst,
                               int E, int thr, int* __restrict__ cursor,
                               int* __restrict__ sorted_src) {
    int i = blockIdx.x * blockDim.x + threadIdx.x;
    if (i < E) {
        int k = dst[i] * 2 + (src[i] >= thr);
        int p = atomicAdd(&cursor[k], 1);
        sorted_src[p] = src[i];
    }
}

// ---------------------------------------------------------------------------
// Gather: one 64-lane wave per dst row, 4-edge unroll.
// MODE 0: single pass, normalize.  (rows = rs[r]..rs[r+1])
// MODE 1: pass A (lower src half), write RAW sums.   (segment rs[2r]..rs[2r+1])
// MODE 2: pass B (upper src half), add + normalize.  (segment rs[2r+1]..rs[2r+2])
// ---------------------------------------------------------------------------
template <int F, int MODE>
__global__ __launch_bounds__(256) void gather_k(const float* __restrict__ h,
                                                const int* __restrict__ rs,
                                                const int* __restrict__ ss,
                                                float* __restrict__ out, int N) {
    int lane = threadIdx.x & 63;
    int r = blockIdx.x * 4 + (threadIdx.x >> 6);
    if (r >= N) return;
    int s0, s1, tot;
    if constexpr (MODE == 0) {
        s0 = rs[r]; s1 = rs[r + 1]; tot = s1 - s0;
    } else if constexpr (MODE == 1) {
        s0 = rs[2 * r]; s1 = rs[2 * r + 1]; tot = 0;
    } else {
        int b = rs[2 * r]; s0 = rs[2 * r + 1]; s1 = rs[2 * r + 2]; tot = s1 - b;
    }

    if constexpr (F == 256) {
        const float* hp = h + (size_t)lane * 4;
        float4 prev = make_float4(0.f, 0.f, 0.f, 0.f);
        if constexpr (MODE == 2)
            prev = *(const float4*)(out + (size_t)r * F + lane * 4);
        float4 acc = make_float4(0.f, 0.f, 0.f, 0.f);
        int e = s0;
        for (; e + 3 < s1; e += 4) {
            int ia = ss[e], ib = ss[e + 1], ic = ss[e + 2], id = ss[e + 3];
            float4 va = *(const float4*)(hp + (size_t)ia * F);
            float4 vb = *(const float4*)(hp + (size_t)ib * F);
            float4 vc = *(const float4*)(hp + (size_t)ic * F);
            float4 vd = *(const float4*)(hp + (size_t)id * F);
            acc.x += (va.x + vb.x) + (vc.x + vd.x);
            acc.y += (va.y + vb.y) + (vc.y + vd.y);
            acc.z += (va.z + vb.z) + (vc.z + vd.z);
            acc.w += (va.w + vb.w) + (vc.w + vd.w);
        }
        for (; e < s1; ++e) {
            int ia = ss[e];
            float4 va = *(const float4*)(hp + (size_t)ia * F);
            acc.x += va.x; acc.y += va.y; acc.z += va.z; acc.w += va.w;
        }
        float4 o;
        if constexpr (MODE == 1) {
            o = acc;
        } else {
            float inv = (tot > 0) ? 1.0f / (float)tot : 0.0f;
            o.x = (acc.x + prev.x) * inv;
            o.y = (acc.y + prev.y) * inv;
            o.z = (acc.z + prev.z) * inv;
            o.w = (acc.w + prev.w) * inv;
        }
        *(float4*)(out + (size_t)r * F + lane * 4) = o;
    } else {  // F == 128, MODE 0 only
        const float* hp = h + (size_t)lane * 2;
        float2 acc = make_float2(0.f, 0.f);
        int e = s0;
        for (; e + 3 < s1; e += 4) {
            int ia = ss[e], ib = ss[e + 1], ic = ss[e + 2], id = ss[e + 3];
            float2 va = *(const float2*)(hp + (size_t)ia * F);
            float2 vb = *(const float2*)(hp + (size_t)ib * F);
            float2 vc = *(const float2*)(hp + (size_t)ic * F);
            float2 vd = *(const float2*)(hp + (size_t)id * F);
            acc.x += (va.x + vb.x) + (vc.x + vd.x);
            acc.y += (va.y + vb.y) + (vc.y + vd.y);
        }
        for (; e < s1; ++e) {
            int ia = ss[e];
            float2 va = *(const float2*)(hp + (size_t)ia * F);
            acc.x += va.x; acc.y += va.y;
        }
        float inv = (tot > 0) ? 1.0f / (float)tot : 0.0f;
        *(float2*)(out + (size_t)r * F + lane * 2) = make_float2(acc.x * inv, acc.y * inv);
    }
}

// ---------------------------------------------------------------------------
// Register-tiled fp32 GEMM for FOUT=128: C[N,128] = A[N,FIN] @ W[FIN,128] + b
// 128x128 tile per block, 256 threads, 8x8 outputs/thread, k-tiled LDS.
// ---------------------------------------------------------------------------
template <int FIN, bool RELU>
__global__ __launch_bounds__(256) void linear128(const float* __restrict__ A,
                                                 const float* __restrict__ W,
                                                 const float* __restrict__ bias,
                                                 float* __restrict__ out, int N) {
    constexpr int KB = 32;
    __shared__ float as[KB][132];  // k-major A tile, padded
    __shared__ float ws[KB][128];  // k-major W tile
    int tx = threadIdx.x & 15;
    int ty = threadIdx.x >> 4;
    int rbase = blockIdx.x * 128;

    float acc[8][8];
#pragma unroll
    for (int i = 0; i < 8; ++i)
#pragma unroll
        for (int j = 0; j < 8; ++j) acc[i][j] = 0.f;

    for (int k0 = 0; k0 < FIN; k0 += KB) {
        // stage A: 128 rows x KB k.  8 lanes cover one row's 128B chunk.
#pragma unroll
        for (int f = threadIdx.x; f < 1024; f += 256) {
            int row = f >> 3;
            int kk = (f & 7) * 4;
            int gr = rbase + row;
            float4 v = (gr < N) ? *(const float4*)&A[(size_t)gr * FIN + k0 + kk]
                                : make_float4(0.f, 0.f, 0.f, 0.f);
            as[kk + 0][row] = v.x;
            as[kk + 1][row] = v.y;
            as[kk + 2][row] = v.z;
            as[kk + 3][row] = v.w;
        }
        // stage W: KB x 128
#pragma unroll
        for (int f = threadIdx.x; f < 1024; f += 256) {
            int c = (f & 31) * 4;
            int kk = f >> 5;
            *(float4*)&ws[kk][c] = *(const float4*)&W[(size_t)(k0 + kk) * 128 + c];
        }
        __syncthreads();
#pragma unroll
        for (int kk = 0; kk < KB; ++kk) {
            float4 a0 = *(const float4*)&as[kk][ty * 4];
            float4 a1 = *(const float4*)&as[kk][64 + ty * 4];
            float4 w0 = *(const float4*)&ws[kk][tx * 4];
            float4 w1 = *(const float4*)&ws[kk][64 + tx * 4];
            float a[8] = {a0.x, a0.y, a0.z, a0.w, a1.x, a1.y, a1.z, a1.w};
            float w[8] = {w0.x, w0.y, w0.z, w0.w, w1.x, w1.y, w1.z, w1.w};
#pragma unroll
            for (int i = 0; i < 8; ++i)
#pragma unroll
                for (int j = 0; j < 8; ++j) acc[i][j] += a[i] * w[j];
        }
        __syncthreads();
    }

    float4 bb0 = *(const float4*)&bias[tx * 4];
    float4 bb1 = *(const float4*)&bias[64 + tx * 4];
#pragma unroll
    for (int i = 0; i < 8; ++i) {
        int row = rbase + (i < 4 ? ty * 4 + i : 64 + ty * 4 + (i - 4));
        if (row < N) {
            float4 o0 = make_float4(acc[i][0] + bb0.x, acc[i][1] + bb0.y,
                                    acc[i][2] + bb0.z, acc[i][3] + bb0.w);
            float4 o1 = make_float4(acc[i][4] + bb1.x, acc[i][5] + bb1.y,
                                    acc[i][6] + bb1.z, acc[i][7] + bb1.w);
            if (RELU) {
                o0.x = fmaxf(o0.x, 0.f); o0.y = fmaxf(o0.y, 0.f);
                o0.z = fmaxf(o0.z, 0.f); o0.w = fmaxf(o0.w, 0.f);
                o1.x = fmaxf(o1.x, 0.f); o1.y = fmaxf(o1.y, 0.f);
                o1.z = fmaxf(o1.z, 0.f); o1.w = fmaxf(o1.w, 0.f);
            }
            *(float4*)&out[(size_t)row * 128 + tx * 4] = o0;
            *(float4*)&out[(size_t)row * 128 + 64 + tx * 4] = o1;
        }
    }
}

// ---------------------------------------------------------------------------
// Small linear for the 47-col output layer (one block = 8 rows).
// ---------------------------------------------------------------------------
template <int FIN, int FOUT, int CTH, int RPB, bool RELU>
__global__ __launch_bounds__(256) void linear_kernel(const float* __restrict__ in,
                                                     const float* __restrict__ W,
                                                     const float* __restrict__ b,
                                                     float* __restrict__ out, int N) {
    constexpr int RG = 256 / CTH;
    constexpr int RPT = RPB / RG;
    __shared__ __align__(16) float rows[RPB][FIN];
    int rbase = blockIdx.x * RPB;

    for (int idx = threadIdx.x * 4; idx < RPB * FIN; idx += 256 * 4) {
        *(float4*)&rows[0][idx] = *(const float4*)&in[(size_t)rbase * FIN + idx];
    }
    __syncthreads();

    int j = threadIdx.x % CTH;
    int rg = threadIdx.x / CTH;
    if (j < FOUT) {
        float acc[RPT];
#pragma unroll
        for (int r = 0; r < RPT; ++r) acc[r] = 0.f;
#pragma unroll 8
        for (int k = 0; k < FIN; ++k) {
            float w = W[k * FOUT + j];
#pragma unroll
            for (int r = 0; r < RPT; ++r)
                acc[r] += rows[rg * RPT + r][k] * w;
        }
        float bb = b[j];
#pragma unroll
        for (int r = 0; r < RPT; ++r) {
            float v = acc[r] + bb;
            if (RELU) v = fmaxf(v, 0.f);
            out[(size_t)(rbase + rg * RPT + r) * FOUT + j] = v;
        }
    }
}

// ---------------------------------------------------------------------------

static inline size_t align256(size_t x) { return (x + 255) & ~size_t(255); }

extern "C" void kernel_launch(void* const* d_in, const int* in_sizes, int n_in,
                              void* d_out, int out_size, void* d_ws, size_t ws_size,
                              hipStream_t stream) {
    const float* features = (const float*)d_in[0];
    const int*   src0     = (const int*)d_in[1];
    const int*   dst0     = (const int*)d_in[2];
    const int*   src1     = (const int*)d_in[3];
    const int*   dst1     = (const int*)d_in[4];
    const int*   src2     = (const int*)d_in[5];
    const int*   dst2     = (const int*)d_in[6];
    const float* W1       = (const float*)d_in[7];
    const float* b1       = (const float*)d_in[8];
    const float* W2       = (const float*)d_in[9];
    const float* b2       = (const float*)d_in[10];
    const float* W3       = (const float*)d_in[11];
    const float* b3       = (const float*)d_in[12];
    float* out = (float*)d_out;

    char* p = (char*)d_ws;
    size_t off = 0;
    auto alloc = [&](size_t bytes) {
        char* r = p + off;
        off += align256(bytes);
        return r;
    };
    float* mean0 = (float*)alloc(sizeof(float) * (size_t)NL1 * F_IN);
    float* h1    = (float*)alloc(sizeof(float) * (size_t)NL1 * F_HID);
    float* mean1 = (float*)alloc(sizeof(float) * (size_t)NL2 * F_HID);
    float* h2    = (float*)alloc(sizeof(float) * (size_t)NL2 * F_HID);
    float* mean2 = (float*)alloc(sizeof(float) * (size_t)NL3 * F_HID);
    // layer 0 (split: 2*NL1 virtual rows)
    int* cnt0 = (int*)alloc(sizeof(int) * 2 * NL1);
    int* rs0  = (int*)alloc(sizeof(int) * (2 * NL1 + 1));
    int* cur0 = (int*)alloc(sizeof(int) * 2 * NL1);
    int* bs0  = (int*)alloc(sizeof(int) * 1024);
    int* ss0  = (int*)alloc(sizeof(int) * NE0);
    int* cnt1 = (int*)alloc(sizeof(int) * NL2);
    int* rs1  = (int*)alloc(sizeof(int) * (NL2 + 1));
    int* cur1 = (int*)alloc(sizeof(int) * NL2);
    int* bs1  = (int*)alloc(sizeof(int) * 1024);
    int* ss1  = (int*)alloc(sizeof(int) * NE1);
    int* cnt2 = (int*)alloc(sizeof(int) * NL3);
    int* rs2  = (int*)alloc(sizeof(int) * (NL3 + 1));
    int* cur2 = (int*)alloc(sizeof(int) * NL3);
    int* bs2  = (int*)alloc(sizeof(int) * 1024);
    int* ss2  = (int*)alloc(sizeof(int) * NE2);
    (void)ws_size;

    // ---- Layer 0 -> 1 (split CSR over 2*NL1 virtual rows) ----
    {
        const int NN = 2 * NL1;
        hipMemsetAsync(cnt0, 0, sizeof(int) * NN, stream);
        histogram_split<<<(NE0 + 255) / 256, 256, 0, stream>>>(dst0, src0, NE0, THR0, cnt0);
        int nb = (NN + 1023) / 1024;
        scan_block<<<nb, 1024, 0, stream>>>(cnt0, NN, rs0, bs0);
        scan_totals<<<1, 1024, 0, stream>>>(bs0, nb);
        add_offsets<<<nb, 1024, 0, stream>>>(rs0, bs0, NN, NE0, cur0);
        fill_csr_split<<<(NE0 + 255) / 256, 256, 0, stream>>>(src0, dst0, NE0, THR0, cur0, ss0);
    }
    gather_k<F_IN, 1><<<NL1 / 4, 256, 0, stream>>>(features, rs0, ss0, mean0, NL1);
    gather_k<F_IN, 2><<<NL1 / 4, 256, 0, stream>>>(features, rs0, ss0, mean0, NL1);
    linear128<F_IN, true><<<(NL1 + 127) / 128, 256, 0, stream>>>(mean0, W1, b1, h1, NL1);

    auto build_csr = [&](const int* src, const int* dst, int E, int N,
                         int* cnt, int* rs, int* cur, int* bs, int* ss) {
        hipMemsetAsync(cnt, 0, sizeof(int) * N, stream);
        histogram<<<(E + 255) / 256, 256, 0, stream>>>(dst, E, cnt);
        int nb = (N + 1023) / 1024;
        scan_block<<<nb, 1024, 0, stream>>>(cnt, N, rs, bs);
        scan_totals<<<1, 1024, 0, stream>>>(bs, nb);
        add_offsets<<<nb, 1024, 0, stream>>>(rs, bs, N, E, cur);
        fill_csr<<<(E + 255) / 256, 256, 0, stream>>>(src, dst, E, cur, ss);
    };

    // ---- Layer 1 -> 2 ----
    build_csr(src1, dst1, NE1, NL2, cnt1, rs1, cur1, bs1, ss1);
    gather_k<F_HID, 0><<<NL2 / 4, 256, 0, stream>>>(h1, rs1, ss1, mean1, NL2);
    linear128<F_HID, true><<<(NL2 + 127) / 128, 256, 0, stream>>>(mean1, W2, b2, h2, NL2);

    // ---- Layer 2 -> 3 ----
    build_csr(src2, dst2, NE2, NL3, cnt2, rs2, cur2, bs2, ss2);
    gather_k<F_HID, 0><<<NL3 / 4, 256, 0, stream>>>(h2, rs2, ss2, mean2, NL3);
    linear_kernel<F_HID, F_OUT, 64, 8, false><<<NL3 / 8, 256, 0, stream>>>(mean2, W3, b3, out, NL3);
}